// Round 1
// baseline (3489.197 us; speedup 1.0000x reference)
//
#include <hip/hip_runtime.h>
#include <math.h>

#define B_ROWS 4096
#define IN_DIM 1024
#define P_DIM  256
#define C_CLS  5994
#define NSPLIT 8
#define SPLIT_COLS 768   // 6 tiles * 128; 8*768 = 6144 >= 5994

#define AAM_COS_M 0.9800665778412416f
#define AAM_SIN_M 0.19866933079506122f
#define AAM_TH   (-0.9800665778412416f)
#define AAM_MM    0.03973386615901225f
#define AAM_S     30.0f

// ---------------- Kernel 1: e = x @ W_fc^T + b_fc  (M=4096,N=256,K=1024) ----
// 64x64 tile, 256 threads, 4x4 per thread, KT=32 staged in LDS.
__global__ __launch_bounds__(256, 4) void fc_gemm(const float* __restrict__ X,
                                                  const float* __restrict__ Wfc,
                                                  const float* __restrict__ bfc,
                                                  float* __restrict__ E) {
    __shared__ float As[64][36];
    __shared__ float Bs[64][36];
    const int tid = threadIdx.x;
    const int tx = tid & 15, ty = tid >> 4;
    const int rb = blockIdx.x * 64;   // 64 row tiles
    const int cb = blockIdx.y * 64;   // 4 col tiles

    float acc[4][4];
#pragma unroll
    for (int i = 0; i < 4; ++i)
#pragma unroll
        for (int j = 0; j < 4; ++j) acc[i][j] = 0.0f;

    for (int k0 = 0; k0 < IN_DIM; k0 += 32) {
#pragma unroll
        for (int ph = 0; ph < 2; ++ph) {
            int li = tid + ph * 256;          // 0..511
            int r = li >> 3;                  // 0..63
            int kk = (li & 7) << 2;           // 0..28
            *(float4*)&As[r][kk] = *(const float4*)&X[(size_t)(rb + r) * IN_DIM + k0 + kk];
            *(float4*)&Bs[r][kk] = *(const float4*)&Wfc[(size_t)(cb + r) * IN_DIM + k0 + kk];
        }
        __syncthreads();
#pragma unroll
        for (int kk = 0; kk < 32; kk += 4) {
            float4 a[4], b[4];
#pragma unroll
            for (int i = 0; i < 4; ++i) a[i] = *(const float4*)&As[i * 16 + ty][kk];
#pragma unroll
            for (int j = 0; j < 4; ++j) b[j] = *(const float4*)&Bs[j * 16 + tx][kk];
#pragma unroll
            for (int i = 0; i < 4; ++i)
#pragma unroll
                for (int j = 0; j < 4; ++j)
                    acc[i][j] += a[i].x * b[j].x + a[i].y * b[j].y +
                                 a[i].z * b[j].z + a[i].w * b[j].w;
        }
        __syncthreads();
    }
#pragma unroll
    for (int j = 0; j < 4; ++j) {
        float bb = bfc[cb + j * 16 + tx];
#pragma unroll
        for (int i = 0; i < 4; ++i)
            E[(size_t)(rb + i * 16 + ty) * P_DIM + cb + j * 16 + tx] = acc[i][j] + bb;
    }
}

// ---------------- Kernel 2: row L2-normalize (rows of length 256) -----------
__global__ __launch_bounds__(256) void rownorm(const float* __restrict__ src,
                                               float* __restrict__ dst, int nrows) {
    const int wave = threadIdx.x >> 6;
    const int lane = threadIdx.x & 63;
    const int row = blockIdx.x * 4 + wave;
    if (row >= nrows) return;
    float4 v = *(const float4*)&src[(size_t)row * P_DIM + lane * 4];
    float ss = v.x * v.x + v.y * v.y + v.z * v.z + v.w * v.w;
#pragma unroll
    for (int m = 32; m >= 1; m >>= 1) ss += __shfl_xor(ss, m, 64);
    float scale = 1.0f / fmaxf(sqrtf(ss), 1e-12f);
    v.x *= scale; v.y *= scale; v.z *= scale; v.w *= scale;
    *(float4*)&dst[(size_t)row * P_DIM + lane * 4] = v;
}

// ---------------- Kernel 3: cosine GEMM + margin + online softmax partials --
// M=4096, N=5994 (padded 6144), K=256. 128x128 tiles, 8x8 per thread.
// Grid (32 row-tiles, 8 col-splits); each split covers 768 cols = 6 tiles.
__global__ __launch_bounds__(256, 2) void aam_gemm(const float* __restrict__ En,
                                                   const float* __restrict__ Wn,
                                                   const int* __restrict__ label,
                                                   float* __restrict__ pm,
                                                   float* __restrict__ ps,
                                                   float* __restrict__ plab) {
    __shared__ float As[128][36];
    __shared__ float Bs[128][36];
    const int tid = threadIdx.x;
    const int tx = tid & 15, ty = tid >> 4;
    const int rb = blockIdx.x * 128;
    const int split = blockIdx.y;
    const int cbase = split * SPLIT_COLS;

    int labi[8];
#pragma unroll
    for (int i = 0; i < 8; ++i) labi[i] = label[rb + i * 16 + ty];

    float m[8], s[8], lv[8];
#pragma unroll
    for (int i = 0; i < 8; ++i) { m[i] = -INFINITY; s[i] = 0.0f; lv[i] = -1e30f; }

    for (int t = 0; t < 6; ++t) {
        const int cb = cbase + t * 128;
        float acc[8][8];
#pragma unroll
        for (int i = 0; i < 8; ++i)
#pragma unroll
            for (int j = 0; j < 8; ++j) acc[i][j] = 0.0f;

        for (int k0 = 0; k0 < P_DIM; k0 += 32) {
#pragma unroll
            for (int ph = 0; ph < 4; ++ph) {
                int li = tid + ph * 256;      // 0..1023
                int r = li >> 3;              // 0..127
                int kk = (li & 7) << 2;
                *(float4*)&As[r][kk] = *(const float4*)&En[(size_t)(rb + r) * P_DIM + k0 + kk];
                // cb + r may exceed C_CLS-1 (padding): reads stay inside ws (finite garbage),
                // those columns are masked below.
                *(float4*)&Bs[r][kk] = *(const float4*)&Wn[(size_t)(cb + r) * P_DIM + k0 + kk];
            }
            __syncthreads();
#pragma unroll
            for (int kk = 0; kk < 32; kk += 4) {
                float4 a[8], b[8];
#pragma unroll
                for (int i = 0; i < 8; ++i) a[i] = *(const float4*)&As[i * 16 + ty][kk];
#pragma unroll
                for (int j = 0; j < 8; ++j) b[j] = *(const float4*)&Bs[j * 16 + tx][kk];
#pragma unroll
                for (int i = 0; i < 8; ++i)
#pragma unroll
                    for (int j = 0; j < 8; ++j)
                        acc[i][j] += a[i].x * b[j].x + a[i].y * b[j].y +
                                     a[i].z * b[j].z + a[i].w * b[j].w;
            }
            __syncthreads();
        }

        // epilogue: margin + scale + online max/sum
#pragma unroll
        for (int i = 0; i < 8; ++i) {
#pragma unroll
            for (int j = 0; j < 8; ++j) {
                int c = cb + j * 16 + tx;
                if (c < C_CLS) {
                    float cosv = acc[i][j];
                    float v = AAM_S * cosv;
                    if (c == labi[i]) {
                        float sine = sqrtf(fmaxf(1.0f - cosv * cosv, 0.0f));
                        float phi = cosv * AAM_COS_M - sine * AAM_SIN_M;
                        phi = ((cosv - AAM_TH) > 0.0f) ? phi : (cosv - AAM_MM);
                        v = AAM_S * phi;
                        lv[i] = v;
                    }
                    float mn = fmaxf(m[i], v);
                    s[i] = s[i] * __expf(m[i] - mn) + __expf(v - mn);
                    m[i] = mn;
                }
            }
        }
    }

    // reduce (m,s,lv) across the 16 tx-lanes sharing each row
#pragma unroll
    for (int i = 0; i < 8; ++i) {
#pragma unroll
        for (int msk = 1; msk < 16; msk <<= 1) {
            float om = __shfl_xor(m[i], msk, 64);
            float os = __shfl_xor(s[i], msk, 64);
            float ol = __shfl_xor(lv[i], msk, 64);
            float mn = fmaxf(m[i], om);
            float snew = 0.0f;
            if (m[i] > -1e37f) snew += s[i] * __expf(m[i] - mn);
            if (om > -1e37f) snew += os * __expf(om - mn);
            m[i] = mn; s[i] = snew;
            lv[i] = fmaxf(lv[i], ol);
        }
        if (tx == 0) {
            int row = rb + i * 16 + ty;
            pm[split * B_ROWS + row] = m[i];
            ps[split * B_ROWS + row] = s[i];
            plab[split * B_ROWS + row] = lv[i];
        }
    }
}

// ---------------- Kernel 4: merge splits, nll, mean -------------------------
__global__ __launch_bounds__(256) void reduce_nll(const float* __restrict__ pm,
                                                  const float* __restrict__ ps,
                                                  const float* __restrict__ plab,
                                                  float* __restrict__ out) {
    const int row = blockIdx.x * 256 + threadIdx.x;
    float m = -INFINITY, s = 0.0f, lab = -1e30f;
    for (int sp = 0; sp < NSPLIT; ++sp) {
        float om = pm[sp * B_ROWS + row];
        float os = ps[sp * B_ROWS + row];
        float mn = fmaxf(m, om);
        float snew = 0.0f;
        if (m > -1e37f) snew += s * expf(m - mn);
        if (om > -1e37f) snew += os * expf(om - mn);
        m = mn; s = snew;
        lab = fmaxf(lab, plab[sp * B_ROWS + row]);
    }
    float v = (m + logf(s) - lab) * (1.0f / (float)B_ROWS);
#pragma unroll
    for (int msk = 32; msk >= 1; msk >>= 1) v += __shfl_xor(v, msk, 64);
    if ((threadIdx.x & 63) == 0) atomicAdd(out, v);
}

extern "C" void kernel_launch(void* const* d_in, const int* in_sizes, int n_in,
                              void* d_out, int out_size, void* d_ws, size_t ws_size,
                              hipStream_t stream) {
    const float* x    = (const float*)d_in[0];
    const int*   lab  = (const int*)d_in[1];
    const float* Wfc  = (const float*)d_in[2];
    const float* bfc  = (const float*)d_in[3];
    const float* Waam = (const float*)d_in[4];
    float* out = (float*)d_out;

    char* ws = (char*)d_ws;
    float* E    = (float*)ws;                                   // 4096*256 f32 = 4 MiB
    float* Wn   = (float*)(ws + 4194304);                       // 5994*256 f32
    float* pm   = (float*)(ws + 4194304 + 6137856);             // 8*4096
    float* ps_  = pm + NSPLIT * B_ROWS;
    float* plab = ps_ + NSPLIT * B_ROWS;

    hipMemsetAsync(d_out, 0, sizeof(float), stream);

    fc_gemm<<<dim3(64, 4), 256, 0, stream>>>(x, Wfc, bfc, E);
    rownorm<<<B_ROWS / 4, 256, 0, stream>>>(E, E, B_ROWS);
    rownorm<<<(C_CLS + 3) / 4, 256, 0, stream>>>(Waam, Wn, C_CLS);
    aam_gemm<<<dim3(32, NSPLIT), 256, 0, stream>>>(E, Wn, lab, pm, ps_, plab);
    reduce_nll<<<B_ROWS / 256, 256, 0, stream>>>(pm, ps_, plab, out);
}

// Round 3
// 145.612 us; speedup vs baseline: 23.9622x; 23.9622x over previous
//
#include <hip/hip_runtime.h>
#include <math.h>

typedef __attribute__((ext_vector_type(8))) short bf16x8;
typedef __attribute__((ext_vector_type(4))) float f32x4;

#define AAM_COS_M 0.9800665778412416f
#define AAM_SIN_M 0.19866933079506122f
#define AAM_TH   (-0.9800665778412416f)
#define AAM_MM    0.03973386615901225f
#define C_CLS 5994

__device__ inline ushort f2bf(float f) {
    unsigned x = __float_as_uint(f);
    return (ushort)((x + 0x7fffu + ((x >> 16) & 1u)) >> 16);
}
__device__ inline float bflo(unsigned u) { return __uint_as_float(u << 16); }
__device__ inline float bfhi(unsigned u) { return __uint_as_float(u & 0xffff0000u); }

// ---------------- fp32 -> bf16 conversion (vectorized) ----------------------
__global__ __launch_bounds__(256) void to_bf16(const float* __restrict__ s,
                                               ushort* __restrict__ d, int n4) {
    int i = blockIdx.x * 256 + threadIdx.x;
    if (i >= n4) return;
    float4 v = ((const float4*)s)[i];
    ushort4 o;
    o.x = f2bf(v.x); o.y = f2bf(v.y); o.z = f2bf(v.z); o.w = f2bf(v.w);
    ((ushort4*)d)[i] = o;
}

// ---------------- fc GEMM: E = x @ Wfc^T + b (MFMA bf16) --------------------
// M=4096,N=256,K=1024. 128x128 tile, 4 waves, each 64x64 (4x4 frags of 16x16x32).
__global__ __launch_bounds__(256) void fc_mfma(const ushort* __restrict__ A,
                                               const ushort* __restrict__ Bm,
                                               const float* __restrict__ bias,
                                               float* __restrict__ C) {
    __shared__ ushort As[128 * 40];   // stride 40 ushorts = 80B: breaks pow2 banks
    __shared__ ushort Bs[128 * 40];
    const int tid = threadIdx.x;
    const int lane = tid & 63, w = tid >> 6;
    const int wr = w >> 1, wc = w & 1;
    const int lx = lane & 15, lg = lane >> 4;
    const int rb = blockIdx.x * 128, cb = blockIdx.y * 128;

    f32x4 zero = {0.f, 0.f, 0.f, 0.f};
    f32x4 acc[4][4];
#pragma unroll
    for (int i = 0; i < 4; ++i)
#pragma unroll
        for (int j = 0; j < 4; ++j) acc[i][j] = zero;

    for (int k0 = 0; k0 < 1024; k0 += 32) {
#pragma unroll
        for (int p = 0; p < 2; ++p) {
            int q = tid + p * 256;            // 512 loads of 16B per matrix
            int r = q >> 2, ko = (q & 3) << 3;
            *(float4*)&As[r * 40 + ko] = *(const float4*)&A[(size_t)(rb + r) * 1024 + k0 + ko];
            *(float4*)&Bs[r * 40 + ko] = *(const float4*)&Bm[(size_t)(cb + r) * 1024 + k0 + ko];
        }
        __syncthreads();
        bf16x8 af[4], bfr[4];
#pragma unroll
        for (int f = 0; f < 4; ++f) {
            af[f]  = *(const bf16x8*)&As[(wr * 64 + f * 16 + lx) * 40 + lg * 8];
            bfr[f] = *(const bf16x8*)&Bs[(wc * 64 + f * 16 + lx) * 40 + lg * 8];
        }
#pragma unroll
        for (int i = 0; i < 4; ++i)
#pragma unroll
            for (int j = 0; j < 4; ++j)
                acc[i][j] = __builtin_amdgcn_mfma_f32_16x16x32_bf16(af[i], bfr[j], acc[i][j], 0, 0, 0);
        __syncthreads();
    }
    // D: row = wr*64 + i*16 + lg*4 + r, col = wc*64 + j*16 + lx   [m89 layout]
#pragma unroll
    for (int j = 0; j < 4; ++j) {
        int col = cb + wc * 64 + j * 16 + lx;
        float bb = bias[col];
#pragma unroll
        for (int i = 0; i < 4; ++i) {
            int row0 = rb + wr * 64 + i * 16 + lg * 4;
#pragma unroll
            for (int r = 0; r < 4; ++r)
                C[(size_t)(row0 + r) * 256 + col] = acc[i][j][r] + bb;
        }
    }
}

// ---------------- row L2-normalize E (fp32 in) -> bf16 out ------------------
__global__ __launch_bounds__(256) void rownorm_e(const float* __restrict__ E,
                                                 ushort* __restrict__ En) {
    const int wave = threadIdx.x >> 6, lane = threadIdx.x & 63;
    const int row = blockIdx.x * 4 + wave;
    float4 v = ((const float4*)&E[(size_t)row * 256])[lane];
    float ss = v.x * v.x + v.y * v.y + v.z * v.z + v.w * v.w;
#pragma unroll
    for (int m = 32; m >= 1; m >>= 1) ss += __shfl_xor(ss, m, 64);
    float sc = 1.f / fmaxf(sqrtf(ss), 1e-12f);
    ushort4 o;
    o.x = f2bf(v.x * sc); o.y = f2bf(v.y * sc); o.z = f2bf(v.z * sc); o.w = f2bf(v.w * sc);
    ((ushort4*)&En[(size_t)row * 256])[lane] = o;
}

// ---------------- row L2-normalize W_aam -> bf16, zero-pad to 6144 rows -----
__global__ __launch_bounds__(256) void rownorm_w(const float* __restrict__ W,
                                                 ushort* __restrict__ Wn) {
    const int wave = threadIdx.x >> 6, lane = threadIdx.x & 63;
    const int row = blockIdx.x * 4 + wave;
    if (row >= 6144) return;
    ushort4 o;
    if (row < C_CLS) {
        float4 v = ((const float4*)&W[(size_t)row * 256])[lane];
        float ss = v.x * v.x + v.y * v.y + v.z * v.z + v.w * v.w;
#pragma unroll
        for (int m = 32; m >= 1; m >>= 1) ss += __shfl_xor(ss, m, 64);
        float sc = 1.f / fmaxf(sqrtf(ss), 1e-12f);
        o.x = f2bf(v.x * sc); o.y = f2bf(v.y * sc); o.z = f2bf(v.z * sc); o.w = f2bf(v.w * sc);
    } else {
        o.x = 0; o.y = 0; o.z = 0; o.w = 0;
    }
    ((ushort4*)&Wn[(size_t)row * 256])[lane] = o;
}

// ---------------- cosine GEMM + masked online softmax partials --------------
// M=4096, N=6144(pad of 5994), K=256. Grid (32 row-blocks, 16 col-splits),
// each split = 3 tiles of 128 cols. Partials per (split, wave-col-half).
__global__ __launch_bounds__(256) void aam_mfma(const ushort* __restrict__ A,
                                                const ushort* __restrict__ Bm,
                                                float* __restrict__ pm,
                                                float* __restrict__ ps) {
    __shared__ ushort As[128 * 40];
    __shared__ ushort Bs[128 * 40];
    const int tid = threadIdx.x;
    const int lane = tid & 63, w = tid >> 6;
    const int wr = w >> 1, wc = w & 1;
    const int lx = lane & 15, lg = lane >> 4;
    const int rb = blockIdx.x * 128;
    const int split = blockIdx.y;

    float mrun[16], srun[16];
#pragma unroll
    for (int idx = 0; idx < 16; ++idx) { mrun[idx] = -INFINITY; srun[idx] = 0.f; }

    f32x4 zero = {0.f, 0.f, 0.f, 0.f};
    for (int t = 0; t < 3; ++t) {
        const int cb = split * 384 + t * 128;
        f32x4 acc[4][4];
#pragma unroll
        for (int i = 0; i < 4; ++i)
#pragma unroll
            for (int j = 0; j < 4; ++j) acc[i][j] = zero;

        for (int k0 = 0; k0 < 256; k0 += 32) {
#pragma unroll
            for (int p = 0; p < 2; ++p) {
                int q = tid + p * 256;
                int r = q >> 2, ko = (q & 3) << 3;
                *(float4*)&As[r * 40 + ko] = *(const float4*)&A[(size_t)(rb + r) * 256 + k0 + ko];
                *(float4*)&Bs[r * 40 + ko] = *(const float4*)&Bm[(size_t)(cb + r) * 256 + k0 + ko];
            }
            __syncthreads();
            bf16x8 af[4], bfr[4];
#pragma unroll
            for (int f = 0; f < 4; ++f) {
                af[f]  = *(const bf16x8*)&As[(wr * 64 + f * 16 + lx) * 40 + lg * 8];
                bfr[f] = *(const bf16x8*)&Bs[(wc * 64 + f * 16 + lx) * 40 + lg * 8];
            }
#pragma unroll
            for (int i = 0; i < 4; ++i)
#pragma unroll
                for (int j = 0; j < 4; ++j)
                    acc[i][j] = __builtin_amdgcn_mfma_f32_16x16x32_bf16(af[i], bfr[j], acc[i][j], 0, 0, 0);
            __syncthreads();
        }

        // masked online softmax accumulate (plain cosine logits, no label logic)
#pragma unroll
        for (int j = 0; j < 4; ++j) {
            int c = cb + wc * 64 + j * 16 + lx;
            if (c < C_CLS) {
#pragma unroll
                for (int i = 0; i < 4; ++i)
#pragma unroll
                    for (int r = 0; r < 4; ++r) {
                        float v = 30.f * acc[i][j][r];
                        int idx = i * 4 + r;
                        float mn = fmaxf(mrun[idx], v);
                        srun[idx] = srun[idx] * __expf(mrun[idx] - mn) + __expf(v - mn);
                        mrun[idx] = mn;
                    }
            }
        }
    }

    // reduce over the 16 lanes (lx) sharing each row
#pragma unroll
    for (int idx = 0; idx < 16; ++idx) {
#pragma unroll
        for (int msk = 1; msk < 16; msk <<= 1) {
            float om = __shfl_xor(mrun[idx], msk, 64);
            float os = __shfl_xor(srun[idx], msk, 64);
            float mn = fmaxf(mrun[idx], om);
            float sa = (mrun[idx] > -1e37f) ? srun[idx] * __expf(mrun[idx] - mn) : 0.f;
            float sb = (om > -1e37f) ? os * __expf(om - mn) : 0.f;
            mrun[idx] = mn; srun[idx] = sa + sb;
        }
        if (lx == 0) {
            int row = rb + wr * 64 + (idx >> 2) * 16 + lg * 4 + (idx & 3);
            int part = split * 2 + wc;           // 32 partials per row
            pm[part * 4096 + row] = mrun[idx];
            ps[part * 4096 + row] = srun[idx];
        }
    }
}

// ---------------- label cosine: dot(En[row], Wn[label[row]]) ----------------
__global__ __launch_bounds__(256) void cos_label_k(const ushort* __restrict__ En,
                                                   const ushort* __restrict__ Wn,
                                                   const int* __restrict__ lab,
                                                   float* __restrict__ cosl) {
    const int wave = threadIdx.x >> 6, lane = threadIdx.x & 63;
    const int row = blockIdx.x * 4 + wave;
    const int l = lab[row];
    uint2 a = ((const uint2*)&En[(size_t)row * 256])[lane];
    uint2 b = ((const uint2*)&Wn[(size_t)l * 256])[lane];
    float sum = bflo(a.x) * bflo(b.x) + bfhi(a.x) * bfhi(b.x)
              + bflo(a.y) * bflo(b.y) + bfhi(a.y) * bfhi(b.y);
#pragma unroll
    for (int m = 32; m >= 1; m >>= 1) sum += __shfl_xor(sum, m, 64);
    if (lane == 0) cosl[row] = sum;
}

// ---------------- merge partials, apply margin at label, nll, mean ----------
__global__ __launch_bounds__(256) void reduce_nll(const float* __restrict__ pm,
                                                  const float* __restrict__ ps,
                                                  const float* __restrict__ cosl,
                                                  float* __restrict__ out) {
    const int row = blockIdx.x * 256 + threadIdx.x;
    float m = -INFINITY, s = 0.f;
    for (int p = 0; p < 32; ++p) {
        float om = pm[p * 4096 + row];
        float os = ps[p * 4096 + row];
        float mn = fmaxf(m, om);
        float sa = (m > -1e37f) ? s * __expf(m - mn) : 0.f;
        float sb = (om > -1e37f) ? os * __expf(om - mn) : 0.f;
        m = mn; s = sa + sb;
    }
    float cv = cosl[row];
    float sine = sqrtf(fmaxf(1.f - cv * cv, 0.f));
    float phi = cv * AAM_COS_M - sine * AAM_SIN_M;
    phi = ((cv - AAM_TH) > 0.f) ? phi : (cv - AAM_MM);
    float vplain = 30.f * cv, vlab = 30.f * phi;
    // s counted the label column with plain cosine; swap it for phi
    float denom = s - __expf(vplain - m) + __expf(vlab - m);
    float nll = m + logf(denom) - vlab;
    float v = nll * (1.f / 4096.f);
#pragma unroll
    for (int msk = 32; msk >= 1; msk >>= 1) v += __shfl_xor(v, msk, 64);
    if ((threadIdx.x & 63) == 0) atomicAdd(out, v);
}

extern "C" void kernel_launch(void* const* d_in, const int* in_sizes, int n_in,
                              void* d_out, int out_size, void* d_ws, size_t ws_size,
                              hipStream_t stream) {
    const float* x    = (const float*)d_in[0];
    const int*   lab  = (const int*)d_in[1];
    const float* Wfc  = (const float*)d_in[2];
    const float* bfc  = (const float*)d_in[3];
    const float* Waam = (const float*)d_in[4];
    float* out = (float*)d_out;

    char* ws = (char*)d_ws;
    ushort* xb   = (ushort*)(ws);                 // 8 MB   [0, 8388608)
    ushort* Wfcb = (ushort*)(ws + 8388608);       // 512 KB
    float*  E    = (float*) (ws + 8912896);       // 4 MB   [.., 13107200)
    ushort* En   = (ushort*)(ws);                 // 2 MB   overlay on dead xb
    ushort* Wn   = (ushort*)(ws + 2097152);       // 3 MB   overlay on dead xb
    float*  pm   = (float*) (ws + 13107200);      // 512 KB (32 parts x 4096)
    float*  ps   = (float*) (ws + 13631488);      // 512 KB
    float*  cosl = (float*) (ws + 14155776);      // 16 KB

    to_bf16<<<4096, 256, 0, stream>>>(x, xb, 1048576);
    to_bf16<<<256, 256, 0, stream>>>(Wfc, Wfcb, 65536);
    fc_mfma<<<dim3(32, 2), 256, 0, stream>>>(xb, Wfcb, bfc, E);
    rownorm_e<<<1024, 256, 0, stream>>>(E, En);
    rownorm_w<<<1536, 256, 0, stream>>>(Waam, Wn);
    aam_mfma<<<dim3(32, 16), 256, 0, stream>>>(En, Wn, pm, ps);
    cos_label_k<<<1024, 256, 0, stream>>>(En, Wn, lab, cosl);
    hipMemsetAsync(d_out, 0, sizeof(float), stream);
    reduce_nll<<<16, 256, 0, stream>>>(pm, ps, cosl, out);
}